// Round 4
// baseline (157.247 us; speedup 1.0000x reference)
//
#include <hip/hip_runtime.h>
#include <hip/hip_fp8.h>

#define VOCAB 100000
#define DIM 128
#define BATCH 65536
#define N_NEG 10

// gather: 8 lanes/group, 1 element/group, 8 groups/wave, 4 waves/block => 32 elems/block
#define BLOCKS (BATCH / 32)   // 2048 blocks; with VGPR<=64 -> 8 blocks/CU = 32 waves/CU
#define QSCALE 256.0f
#define QINV   (1.0f / 256.0f)

typedef float v4f __attribute__((ext_vector_type(4)));
typedef int   v4i __attribute__((ext_vector_type(4)));
typedef int   v2i __attribute__((ext_vector_type(2)));
typedef float v2f __attribute__((ext_vector_type(2)));

// ---------- fp8 helpers ----------
// NOTE (round-2 lesson): no nontemporal loads anywhere. The working set (~118 MB)
// is LLC-resident across bench iterations; nt bypassed the cache and cost +15 us.
#if __has_builtin(__builtin_amdgcn_cvt_pk_fp8_f32) && __has_builtin(__builtin_amdgcn_cvt_pk_f32_fp8)
__device__ __forceinline__ unsigned int pack4_fp8(float a, float b, float c, float d) {
    int r = __builtin_amdgcn_cvt_pk_fp8_f32(a, b, 0, false);   // bytes 0,1
    r = __builtin_amdgcn_cvt_pk_fp8_f32(c, d, r, true);        // bytes 2,3
    return (unsigned int)r;
}
#else
__device__ __forceinline__ unsigned int pack4_fp8(float a, float b, float c, float d) {
    unsigned int r =  (unsigned int)__hip_fp8_e4m3(a).__x;
    r |= (unsigned int)__hip_fp8_e4m3(b).__x << 8;
    r |= (unsigned int)__hip_fp8_e4m3(c).__x << 16;
    r |= (unsigned int)__hip_fp8_e4m3(d).__x << 24;
    return r;
}
#endif

#if __has_builtin(__builtin_amdgcn_cvt_pk_f32_fp8)
__device__ __forceinline__ void fma4_fp8(float& s, unsigned int x, const float* u) {
    v2f lo = __builtin_amdgcn_cvt_pk_f32_fp8(x, false);
    v2f hi = __builtin_amdgcn_cvt_pk_f32_fp8(x, true);
    s += u[0] * lo.x + u[1] * lo.y + u[2] * hi.x + u[3] * hi.y;
}
#else
__device__ __forceinline__ float fp8_to_f(unsigned int b) {
    __hip_fp8_e4m3 t; t.__x = (__hip_fp8_storage_t)b; return (float)t;
}
__device__ __forceinline__ void fma4_fp8(float& s, unsigned int x, const float* u) {
    s += u[0] * fp8_to_f(x & 0xffu) + u[1] * fp8_to_f((x >> 8) & 0xffu)
       + u[2] * fp8_to_f((x >> 16) & 0xffu) + u[3] * fp8_to_f(x >> 24);
}
#endif

__device__ __forceinline__ float dot16_fp8(uint4 w, const float* uf) {
    float s = 0.0f;
    fma4_fp8(s, w.x, uf + 0);
    fma4_fp8(s, w.y, uf + 4);
    fma4_fp8(s, w.z, uf + 8);
    fma4_fp8(s, w.w, uf + 12);
    return s;
}

// softplus(x)/ln2 = max(y,0) + log2(1+2^-|y|), y = x*log2e  (native exp2/log2)
__device__ __forceinline__ float softplus_log2(float x) {
    const float y = x * 1.44269504f;
    const float t = __builtin_amdgcn_exp2f(-fabsf(y));
    return fmaxf(y, 0.0f) + __builtin_amdgcn_logf(1.0f + t);
}

__global__ void zero_out_kernel(float* out) { out[0] = 0.0f; }

// ---------- quantize v-table (zero-out folded in); plain loads/stores keep LLC warm ----------
__global__ __launch_bounds__(256) void quantize_v_kernel(
    const float4* __restrict__ in, uint4* __restrict__ out, float* __restrict__ loss_out) {
    const int i = blockIdx.x * 256 + threadIdx.x;   // one 16-float group
    if (i == 0) loss_out[0] = 0.0f;
    const float4 a = in[i * 4 + 0];
    const float4 b = in[i * 4 + 1];
    const float4 c = in[i * 4 + 2];
    const float4 d = in[i * 4 + 3];
    uint4 r;
    r.x = pack4_fp8(a.x * QSCALE, a.y * QSCALE, a.z * QSCALE, a.w * QSCALE);
    r.y = pack4_fp8(b.x * QSCALE, b.y * QSCALE, b.z * QSCALE, b.w * QSCALE);
    r.z = pack4_fp8(c.x * QSCALE, c.y * QSCALE, c.z * QSCALE, c.w * QSCALE);
    r.w = pack4_fp8(d.x * QSCALE, d.y * QSCALE, d.z * QSCALE, d.w * QSCALE);
    out[i] = r;
}

// ---------- gather: 1 element per 8-lane group (occupancy experiment) ----------
// Halved per-thread state (one uf[16], 11 accs) + __launch_bounds__(256,8) targets
// VGPR<=64 so all 2048 blocks are co-resident: 32 waves/CU (2x round-3) to hide
// the idx->row gather latency chain.
__global__ __launch_bounds__(256, 8) void skipgram_loss_fp8_kernel(
    const int* __restrict__ pos_u,
    const int* __restrict__ pos_v,
    const int* __restrict__ neg_v,
    const float4* __restrict__ u_weight,   // VOCAB x 32 float4 (fp32)
    const uint4* __restrict__ v8,          // VOCAB x 8 uint4 (fp8, 128 B/row)
    float* __restrict__ out)
{
    const int tid  = threadIdx.x;
    const int lane = tid & 63;
    const int wave = tid >> 6;
    const int sub  = lane & 7;       // 16 B slice within the 128-B fp8 row
    const int grp  = lane >> 3;

    const int b = (blockIdx.x * 4 + wave) * 8 + grp;   // one batch element per group

    // ---- index loads (neg_v + b*10 is always 8B-aligned: 40*b bytes) ----
    const int iu = pos_u[b];
    const int iv = pos_v[b];
    const v2i* __restrict__ np = (const v2i*)(neg_v + (size_t)b * N_NEG);
    const v2i q0 = np[0];
    const v2i q1 = np[1];
    const v2i q2 = np[2];
    const v2i q3 = np[3];
    const v2i q4 = np[4];

    // ---- u row in fp32: this lane's 16 floats ----
    const float4* __restrict__ urow = u_weight + (size_t)iu * 32 + sub * 4;
    float uf[16];
    #pragma unroll
    for (int q = 0; q < 4; ++q) {
        const float4 t = urow[q];
        uf[q * 4 + 0] = t.x; uf[q * 4 + 1] = t.y;
        uf[q * 4 + 2] = t.z; uf[q * 4 + 3] = t.w;
    }

    // slot 0 = positive, slots 1..10 = negatives
    const int idx[N_NEG + 1] = { iv, q0.x, q0.y, q1.x, q1.y, q2.x, q2.y, q3.x, q3.y, q4.x, q4.y };

    float a[N_NEG + 1];
    #pragma unroll
    for (int j = 0; j <= N_NEG; ++j)
        a[j] = dot16_fp8(v8[(size_t)idx[j] * 8 + sub], uf);

    #pragma unroll
    for (int m = 1; m < 8; m <<= 1) {
        #pragma unroll
        for (int j = 0; j <= N_NEG; ++j)
            a[j] += __shfl_xor(a[j], m, 64);
    }

    float s = fminf(fmaxf(a[0] * QINV, -10.0f), 10.0f);
    float loss2 = softplus_log2(-s);
    #pragma unroll
    for (int n = 0; n < N_NEG; ++n)
        loss2 -= softplus_log2(a[n + 1] * QINV);
    float loss = loss2 * 0.69314718f;   // loss(b), uniform across the 8-lane group

    // Butterfly over masks 8,16,32 sums the 8 distinct group values once each.
    #pragma unroll
    for (int m = 8; m < 64; m <<= 1) loss += __shfl_xor(loss, m, 64);

    __shared__ float smem[4];
    if (lane == 0) smem[wave] = loss;
    __syncthreads();
    if (tid == 0)
        atomicAdd(out, (smem[0] + smem[1] + smem[2] + smem[3]) * (1.0f / (float)BATCH));
}

// ---------- fp32 fallback if ws is too small ----------
__device__ __forceinline__ float dot4(float4 a, float4 b) {
    return a.x * b.x + a.y * b.y + a.z * b.z + a.w * b.w;
}

__global__ __launch_bounds__(256) void skipgram_loss_fp32_kernel(
    const int* __restrict__ pos_u,
    const int* __restrict__ pos_v,
    const int* __restrict__ neg_v,
    const float4* __restrict__ u_weight,
    const float4* __restrict__ v_weight,
    float* __restrict__ out)
{
    const int tid  = threadIdx.x;
    const int lane = tid & 63;
    const int wave = tid >> 6;
    const int sub  = lane & 7;
    const int grp  = lane >> 3;

    const int b = ((blockIdx.x * 4 + wave) * 8 + grp);

    const int iu = pos_u[b];
    const int iv = pos_v[b];

    const float4* __restrict__ urow = u_weight + iu * 32;
    float4 u0 = urow[0 * 8 + sub];
    float4 u1 = urow[1 * 8 + sub];
    float4 u2 = urow[2 * 8 + sub];
    float4 u3 = urow[3 * 8 + sub];

    const float4* __restrict__ vrow = v_weight + iv * 32;
    float p = dot4(u0, vrow[0 * 8 + sub]) + dot4(u1, vrow[1 * 8 + sub])
            + dot4(u2, vrow[2 * 8 + sub]) + dot4(u3, vrow[3 * 8 + sub]);

    float nd[N_NEG];
    #pragma unroll
    for (int n = 0; n < N_NEG; ++n) {
        const int idx = neg_v[b * N_NEG + n];
        const float4* __restrict__ wrow = v_weight + idx * 32;
        nd[n] = dot4(u0, wrow[0 * 8 + sub]) + dot4(u1, wrow[1 * 8 + sub])
              + dot4(u2, wrow[2 * 8 + sub]) + dot4(u3, wrow[3 * 8 + sub]);
    }

    #pragma unroll
    for (int m = 1; m < 8; m <<= 1) {
        p += __shfl_xor(p, m, 64);
        #pragma unroll
        for (int n = 0; n < N_NEG; ++n) nd[n] += __shfl_xor(nd[n], m, 64);
    }

    float s = fminf(fmaxf(p, -10.0f), 10.0f);
    float loss2 = softplus_log2(-s);
    #pragma unroll
    for (int n = 0; n < N_NEG; ++n) loss2 -= softplus_log2(nd[n]);
    float loss = loss2 * 0.69314718f;

    #pragma unroll
    for (int m = 8; m < 64; m <<= 1) loss += __shfl_xor(loss, m, 64);

    __shared__ float smem[4];
    if (lane == 0) smem[wave] = loss;
    __syncthreads();
    if (tid == 0)
        atomicAdd(out, (smem[0] + smem[1] + smem[2] + smem[3]) * (1.0f / (float)BATCH));
}

extern "C" void kernel_launch(void* const* d_in, const int* in_sizes, int n_in,
                              void* d_out, int out_size, void* d_ws, size_t ws_size,
                              hipStream_t stream) {
    const int*    pos_u    = (const int*)d_in[0];
    const int*    pos_v    = (const int*)d_in[1];
    const int*    neg_v    = (const int*)d_in[2];
    const float4* u_weight = (const float4*)d_in[3];
    const float4* v_weight = (const float4*)d_in[4];
    float* out = (float*)d_out;

    const size_t table_bytes = (size_t)VOCAB * DIM;        // 12.8 MB fp8
    if (ws_size >= table_bytes) {
        uint4* v8 = (uint4*)d_ws;
        const int qblocks = (VOCAB * DIM / 16) / 256;      // 3125
        quantize_v_kernel<<<qblocks, 256, 0, stream>>>(v_weight, v8, out);
        skipgram_loss_fp8_kernel<<<BLOCKS, 256, 0, stream>>>(
            pos_u, pos_v, neg_v, u_weight, v8, out);
    } else {
        zero_out_kernel<<<1, 1, 0, stream>>>(out);
        skipgram_loss_fp32_kernel<<<BATCH / 32, 256, 0, stream>>>(
            pos_u, pos_v, neg_v, u_weight, v_weight, out);
    }
}

// Round 5
// 148.368 us; speedup vs baseline: 1.0598x; 1.0598x over previous
//
#include <hip/hip_runtime.h>
#include <hip/hip_fp8.h>

#define VOCAB 100000
#define DIM 128
#define BATCH 65536
#define N_NEG 10

// gather: 8 lanes/group, 1 element/group, 8 groups/wave, 4 waves/block => 32 elems/block
#define BLOCKS (BATCH / 32)   // 2048
#define QSCALE 256.0f
#define QINV   (1.0f / 256.0f)

typedef float v4f __attribute__((ext_vector_type(4)));
typedef int   v4i __attribute__((ext_vector_type(4)));
typedef int   v2i __attribute__((ext_vector_type(2)));
typedef float v2f __attribute__((ext_vector_type(2)));

// ---------- fp8 helpers ----------
// Round-2 lesson: no nontemporal anywhere (costs +15us; harness fills evict LLC anyway).
// Round-4 lesson: the gather is HBM-miss-LATENCY-bound (1.2 TB/s, VALU 14%). Don't
// squeeze VGPR (bounds(256,8) -> 24 VGPR killed per-lane MLP). This version batches
// all 11 row-gathers into registers before consuming them.
#if __has_builtin(__builtin_amdgcn_cvt_pk_fp8_f32) && __has_builtin(__builtin_amdgcn_cvt_pk_f32_fp8)
__device__ __forceinline__ unsigned int pack4_fp8(float a, float b, float c, float d) {
    int r = __builtin_amdgcn_cvt_pk_fp8_f32(a, b, 0, false);   // bytes 0,1
    r = __builtin_amdgcn_cvt_pk_fp8_f32(c, d, r, true);        // bytes 2,3
    return (unsigned int)r;
}
#else
__device__ __forceinline__ unsigned int pack4_fp8(float a, float b, float c, float d) {
    unsigned int r =  (unsigned int)__hip_fp8_e4m3(a).__x;
    r |= (unsigned int)__hip_fp8_e4m3(b).__x << 8;
    r |= (unsigned int)__hip_fp8_e4m3(c).__x << 16;
    r |= (unsigned int)__hip_fp8_e4m3(d).__x << 24;
    return r;
}
#endif

#if __has_builtin(__builtin_amdgcn_cvt_pk_f32_fp8)
__device__ __forceinline__ void fma4_fp8(float& s, unsigned int x, const float* u) {
    v2f lo = __builtin_amdgcn_cvt_pk_f32_fp8(x, false);
    v2f hi = __builtin_amdgcn_cvt_pk_f32_fp8(x, true);
    s += u[0] * lo.x + u[1] * lo.y + u[2] * hi.x + u[3] * hi.y;
}
#else
__device__ __forceinline__ float fp8_to_f(unsigned int b) {
    __hip_fp8_e4m3 t; t.__x = (__hip_fp8_storage_t)b; return (float)t;
}
__device__ __forceinline__ void fma4_fp8(float& s, unsigned int x, const float* u) {
    s += u[0] * fp8_to_f(x & 0xffu) + u[1] * fp8_to_f((x >> 8) & 0xffu)
       + u[2] * fp8_to_f((x >> 16) & 0xffu) + u[3] * fp8_to_f(x >> 24);
}
#endif

__device__ __forceinline__ float dot16_fp8(uint4 w, const float* uf) {
    float s = 0.0f;
    fma4_fp8(s, w.x, uf + 0);
    fma4_fp8(s, w.y, uf + 4);
    fma4_fp8(s, w.z, uf + 8);
    fma4_fp8(s, w.w, uf + 12);
    return s;
}

// softplus(x)/ln2 = max(y,0) + log2(1+2^-|y|), y = x*log2e  (native exp2/log2)
__device__ __forceinline__ float softplus_log2(float x) {
    const float y = x * 1.44269504f;
    const float t = __builtin_amdgcn_exp2f(-fabsf(y));
    return fmaxf(y, 0.0f) + __builtin_amdgcn_logf(1.0f + t);
}

__global__ void zero_out_kernel(float* out) { out[0] = 0.0f; }

// ---------- quantize v-table (zero-out folded in) ----------
__global__ __launch_bounds__(256) void quantize_v_kernel(
    const float4* __restrict__ in, uint4* __restrict__ out, float* __restrict__ loss_out) {
    const int i = blockIdx.x * 256 + threadIdx.x;   // one 16-float group
    if (i == 0) loss_out[0] = 0.0f;
    const float4 a = in[i * 4 + 0];
    const float4 b = in[i * 4 + 1];
    const float4 c = in[i * 4 + 2];
    const float4 d = in[i * 4 + 3];
    uint4 r;
    r.x = pack4_fp8(a.x * QSCALE, a.y * QSCALE, a.z * QSCALE, a.w * QSCALE);
    r.y = pack4_fp8(b.x * QSCALE, b.y * QSCALE, b.z * QSCALE, b.w * QSCALE);
    r.z = pack4_fp8(c.x * QSCALE, c.y * QSCALE, c.z * QSCALE, c.w * QSCALE);
    r.w = pack4_fp8(d.x * QSCALE, d.y * QSCALE, d.z * QSCALE, d.w * QSCALE);
    out[i] = r;
}

// ---------- gather: 1 element per 8-lane group, batched-MLP version ----------
// All 11 v8 row-gathers land in an unrolled uint4 w[11] (44 VGPR) and the 4 u-row
// loads are co-issued, so ~15 independent 16B loads per lane overlap in ONE HBM
// latency epoch. bounds(256,4) gives the 128-VGPR budget this needs.
__global__ __launch_bounds__(256, 4) void skipgram_loss_fp8_kernel(
    const int* __restrict__ pos_u,
    const int* __restrict__ pos_v,
    const int* __restrict__ neg_v,
    const float4* __restrict__ u_weight,   // VOCAB x 32 float4 (fp32)
    const uint4* __restrict__ v8,          // VOCAB x 8 uint4 (fp8, 128 B/row)
    float* __restrict__ out)
{
    const int tid  = threadIdx.x;
    const int lane = tid & 63;
    const int wave = tid >> 6;
    const int sub  = lane & 7;       // 16 B slice within the 128-B fp8 row
    const int grp  = lane >> 3;

    const int b = (blockIdx.x * 4 + wave) * 8 + grp;   // one batch element per group

    // ---- index loads (neg_v + b*10 is 8B-aligned: 40*b bytes) ----
    const int iu = pos_u[b];
    const int iv = pos_v[b];
    const v2i* __restrict__ np = (const v2i*)(neg_v + (size_t)b * N_NEG);
    const v2i q0 = np[0];
    const v2i q1 = np[1];
    const v2i q2 = np[2];
    const v2i q3 = np[3];
    const v2i q4 = np[4];

    // slot 0 = positive, slots 1..10 = negatives
    const int idx[N_NEG + 1] = { iv, q0.x, q0.y, q1.x, q1.y, q2.x, q2.y, q3.x, q3.y, q4.x, q4.y };

    // ---- PHASE 1: issue ALL data loads (11 gathers + 4 u-row loads) ----
    uint4 w[N_NEG + 1];
    #pragma unroll
    for (int j = 0; j <= N_NEG; ++j)
        w[j] = v8[(size_t)idx[j] * 8 + sub];

    const float4* __restrict__ urow = u_weight + (size_t)iu * 32 + sub * 4;
    const float4 t0 = urow[0];
    const float4 t1 = urow[1];
    const float4 t2 = urow[2];
    const float4 t3 = urow[3];

    // ---- PHASE 2: consume ----
    float uf[16];
    uf[0]  = t0.x; uf[1]  = t0.y; uf[2]  = t0.z; uf[3]  = t0.w;
    uf[4]  = t1.x; uf[5]  = t1.y; uf[6]  = t1.z; uf[7]  = t1.w;
    uf[8]  = t2.x; uf[9]  = t2.y; uf[10] = t2.z; uf[11] = t2.w;
    uf[12] = t3.x; uf[13] = t3.y; uf[14] = t3.z; uf[15] = t3.w;

    float a[N_NEG + 1];
    #pragma unroll
    for (int j = 0; j <= N_NEG; ++j)
        a[j] = dot16_fp8(w[j], uf);

    #pragma unroll
    for (int m = 1; m < 8; m <<= 1) {
        #pragma unroll
        for (int j = 0; j <= N_NEG; ++j)
            a[j] += __shfl_xor(a[j], m, 64);
    }

    float s = fminf(fmaxf(a[0] * QINV, -10.0f), 10.0f);
    float loss2 = softplus_log2(-s);
    #pragma unroll
    for (int n = 0; n < N_NEG; ++n)
        loss2 -= softplus_log2(a[n + 1] * QINV);
    float loss = loss2 * 0.69314718f;   // loss(b), uniform across the 8-lane group

    // Butterfly over masks 8,16,32 sums the 8 distinct group values once each.
    #pragma unroll
    for (int m = 8; m < 64; m <<= 1) loss += __shfl_xor(loss, m, 64);

    __shared__ float smem[4];
    if (lane == 0) smem[wave] = loss;
    __syncthreads();
    if (tid == 0)
        atomicAdd(out, (smem[0] + smem[1] + smem[2] + smem[3]) * (1.0f / (float)BATCH));
}

// ---------- fp32 fallback if ws is too small ----------
__device__ __forceinline__ float dot4(float4 a, float4 b) {
    return a.x * b.x + a.y * b.y + a.z * b.z + a.w * b.w;
}

__global__ __launch_bounds__(256) void skipgram_loss_fp32_kernel(
    const int* __restrict__ pos_u,
    const int* __restrict__ pos_v,
    const int* __restrict__ neg_v,
    const float4* __restrict__ u_weight,
    const float4* __restrict__ v_weight,
    float* __restrict__ out)
{
    const int tid  = threadIdx.x;
    const int lane = tid & 63;
    const int wave = tid >> 6;
    const int sub  = lane & 7;
    const int grp  = lane >> 3;

    const int b = ((blockIdx.x * 4 + wave) * 8 + grp);

    const int iu = pos_u[b];
    const int iv = pos_v[b];

    const float4* __restrict__ urow = u_weight + iu * 32;
    float4 u0 = urow[0 * 8 + sub];
    float4 u1 = urow[1 * 8 + sub];
    float4 u2 = urow[2 * 8 + sub];
    float4 u3 = urow[3 * 8 + sub];

    const float4* __restrict__ vrow = v_weight + iv * 32;
    float p = dot4(u0, vrow[0 * 8 + sub]) + dot4(u1, vrow[1 * 8 + sub])
            + dot4(u2, vrow[2 * 8 + sub]) + dot4(u3, vrow[3 * 8 + sub]);

    float nd[N_NEG];
    #pragma unroll
    for (int n = 0; n < N_NEG; ++n) {
        const int idx = neg_v[b * N_NEG + n];
        const float4* __restrict__ wrow = v_weight + idx * 32;
        nd[n] = dot4(u0, wrow[0 * 8 + sub]) + dot4(u1, wrow[1 * 8 + sub])
              + dot4(u2, wrow[2 * 8 + sub]) + dot4(u3, wrow[3 * 8 + sub]);
    }

    #pragma unroll
    for (int m = 1; m < 8; m <<= 1) {
        p += __shfl_xor(p, m, 64);
        #pragma unroll
        for (int n = 0; n < N_NEG; ++n) nd[n] += __shfl_xor(nd[n], m, 64);
    }

    float s = fminf(fmaxf(p, -10.0f), 10.0f);
    float loss2 = softplus_log2(-s);
    #pragma unroll
    for (int n = 0; n < N_NEG; ++n) loss2 -= softplus_log2(nd[n]);
    float loss = loss2 * 0.69314718f;

    #pragma unroll
    for (int m = 8; m < 64; m <<= 1) loss += __shfl_xor(loss, m, 64);

    __shared__ float smem[4];
    if (lane == 0) smem[wave] = loss;
    __syncthreads();
    if (tid == 0)
        atomicAdd(out, (smem[0] + smem[1] + smem[2] + smem[3]) * (1.0f / (float)BATCH));
}

extern "C" void kernel_launch(void* const* d_in, const int* in_sizes, int n_in,
                              void* d_out, int out_size, void* d_ws, size_t ws_size,
                              hipStream_t stream) {
    const int*    pos_u    = (const int*)d_in[0];
    const int*    pos_v    = (const int*)d_in[1];
    const int*    neg_v    = (const int*)d_in[2];
    const float4* u_weight = (const float4*)d_in[3];
    const float4* v_weight = (const float4*)d_in[4];
    float* out = (float*)d_out;

    const size_t table_bytes = (size_t)VOCAB * DIM;        // 12.8 MB fp8
    if (ws_size >= table_bytes) {
        uint4* v8 = (uint4*)d_ws;
        const int qblocks = (VOCAB * DIM / 16) / 256;      // 3125
        quantize_v_kernel<<<qblocks, 256, 0, stream>>>(v_weight, v8, out);
        skipgram_loss_fp8_kernel<<<BLOCKS, 256, 0, stream>>>(
            pos_u, pos_v, neg_v, u_weight, v8, out);
    } else {
        zero_out_kernel<<<1, 1, 0, stream>>>(out);
        skipgram_loss_fp32_kernel<<<BATCH / 32, 256, 0, stream>>>(
            pos_u, pos_v, neg_v, u_weight, v_weight, out);
    }
}

// Round 6
// 140.097 us; speedup vs baseline: 1.1224x; 1.0590x over previous
//
#include <hip/hip_runtime.h>
#include <hip/hip_fp8.h>

#define VOCAB 100000
#define DIM 128
#define BATCH 65536
#define N_NEG 10

// 8 lanes/group, 2 elements/group, 8 groups/wave, 4 waves/block => 64 elems/block
#define BLOCKS (BATCH / 64)   // 1024
#define QSCALE 256.0f
#define QINV   (1.0f / 256.0f)

typedef float v4f __attribute__((ext_vector_type(4)));
typedef int   v4i __attribute__((ext_vector_type(4)));
typedef int   v2i __attribute__((ext_vector_type(2)));
typedef float v2f __attribute__((ext_vector_type(2)));

// ---------- fp8 helpers ----------
// Round-2 lesson: no nontemporal loads (harness fills stream 512MB/iter through LLC;
// nt additionally bypassed cache for reused data, +15us).
// Round-4/5 lesson: gather is HBM-miss-LATENCY-bound. Perf tracks
// (waves/CU) x (loads-in-flight/lane). This version maxes the product:
// 2 elems/group (30 loads/lane available) + full register batch (bounds(256,3),
// VGPR<=~168 so all 22 v8-gathers + 8 u-loads fly at once) at 12 waves/CU.
#if __has_builtin(__builtin_amdgcn_cvt_pk_fp8_f32) && __has_builtin(__builtin_amdgcn_cvt_pk_f32_fp8)
__device__ __forceinline__ unsigned int pack4_fp8(float a, float b, float c, float d) {
    int r = __builtin_amdgcn_cvt_pk_fp8_f32(a, b, 0, false);   // bytes 0,1
    r = __builtin_amdgcn_cvt_pk_fp8_f32(c, d, r, true);        // bytes 2,3
    return (unsigned int)r;
}
#else
__device__ __forceinline__ unsigned int pack4_fp8(float a, float b, float c, float d) {
    unsigned int r =  (unsigned int)__hip_fp8_e4m3(a).__x;
    r |= (unsigned int)__hip_fp8_e4m3(b).__x << 8;
    r |= (unsigned int)__hip_fp8_e4m3(c).__x << 16;
    r |= (unsigned int)__hip_fp8_e4m3(d).__x << 24;
    return r;
}
#endif

#if __has_builtin(__builtin_amdgcn_cvt_pk_f32_fp8)
__device__ __forceinline__ void fma4_fp8(float& s, unsigned int x, const float* u) {
    v2f lo = __builtin_amdgcn_cvt_pk_f32_fp8(x, false);
    v2f hi = __builtin_amdgcn_cvt_pk_f32_fp8(x, true);
    s += u[0] * lo.x + u[1] * lo.y + u[2] * hi.x + u[3] * hi.y;
}
#else
__device__ __forceinline__ float fp8_to_f(unsigned int b) {
    __hip_fp8_e4m3 t; t.__x = (__hip_fp8_storage_t)b; return (float)t;
}
__device__ __forceinline__ void fma4_fp8(float& s, unsigned int x, const float* u) {
    s += u[0] * fp8_to_f(x & 0xffu) + u[1] * fp8_to_f((x >> 8) & 0xffu)
       + u[2] * fp8_to_f((x >> 16) & 0xffu) + u[3] * fp8_to_f(x >> 24);
}
#endif

__device__ __forceinline__ float dot16_fp8(uint4 w, const float* uf) {
    float s = 0.0f;
    fma4_fp8(s, w.x, uf + 0);
    fma4_fp8(s, w.y, uf + 4);
    fma4_fp8(s, w.z, uf + 8);
    fma4_fp8(s, w.w, uf + 12);
    return s;
}

// softplus(x)/ln2 = max(y,0) + log2(1+2^-|y|), y = x*log2e  (native exp2/log2)
__device__ __forceinline__ float softplus_log2(float x) {
    const float y = x * 1.44269504f;
    const float t = __builtin_amdgcn_exp2f(-fabsf(y));
    return fmaxf(y, 0.0f) + __builtin_amdgcn_logf(1.0f + t);
}

__global__ void zero_out_kernel(float* out) { out[0] = 0.0f; }

// ---------- quantize v-table (zero-out folded in) ----------
__global__ __launch_bounds__(256) void quantize_v_kernel(
    const float4* __restrict__ in, uint4* __restrict__ out, float* __restrict__ loss_out) {
    const int i = blockIdx.x * 256 + threadIdx.x;   // one 16-float group
    if (i == 0) loss_out[0] = 0.0f;
    const float4 a = in[i * 4 + 0];
    const float4 b = in[i * 4 + 1];
    const float4 c = in[i * 4 + 2];
    const float4 d = in[i * 4 + 3];
    uint4 r;
    r.x = pack4_fp8(a.x * QSCALE, a.y * QSCALE, a.z * QSCALE, a.w * QSCALE);
    r.y = pack4_fp8(b.x * QSCALE, b.y * QSCALE, b.z * QSCALE, b.w * QSCALE);
    r.z = pack4_fp8(c.x * QSCALE, c.y * QSCALE, c.z * QSCALE, c.w * QSCALE);
    r.w = pack4_fp8(d.x * QSCALE, d.y * QSCALE, d.z * QSCALE, d.w * QSCALE);
    out[i] = r;
}

// ---------- gather: 2 elements per 8-lane group, FULL register batch ----------
__global__ __launch_bounds__(256, 3) void skipgram_loss_fp8_kernel(
    const int* __restrict__ pos_u,
    const int* __restrict__ pos_v,
    const int* __restrict__ neg_v,
    const float4* __restrict__ u_weight,   // VOCAB x 32 float4 (fp32)
    const uint4* __restrict__ v8,          // VOCAB x 8 uint4 (fp8, 128 B/row)
    float* __restrict__ out)
{
    const int tid  = threadIdx.x;
    const int lane = tid & 63;
    const int wave = tid >> 6;
    const int sub  = lane & 7;       // 16 B slice within the 128-B fp8 row
    const int grp  = lane >> 3;

    const int gg = (blockIdx.x * 4 + wave) * 8 + grp;  // global group id
    const int b0 = gg * 2;                              // even

    // ---- vectorized index loads ----
    const v2i pu = *(const v2i*)(pos_u + b0);
    const v2i pv = *(const v2i*)(pos_v + b0);
    const v4i* __restrict__ np = (const v4i*)(neg_v + (size_t)b0 * N_NEG);  // 80B, 16B-aligned
    const v4i q0 = np[0];
    const v4i q1 = np[1];
    const v4i q2 = np[2];
    const v4i q3 = np[3];
    const v4i q4 = np[4];

    // slot 0 = positive, slots 1..10 = negatives
    const int i0[N_NEG + 1] = { pv.x, q0.x, q0.y, q0.z, q0.w, q1.x, q1.y, q1.z, q1.w, q2.x, q2.y };
    const int i1[N_NEG + 1] = { pv.y, q2.z, q2.w, q3.x, q3.y, q3.z, q3.w, q4.x, q4.y, q4.z, q4.w };

    // ---- PHASE 1: issue ALL data loads (22 v8 gathers + 8 u-row loads) ----
    uint4 w0[N_NEG + 1], w1[N_NEG + 1];
    #pragma unroll
    for (int j = 0; j <= N_NEG; ++j) {
        w0[j] = v8[(size_t)i0[j] * 8 + sub];
        w1[j] = v8[(size_t)i1[j] * 8 + sub];
    }
    const float4* __restrict__ urow0 = u_weight + (size_t)pu.x * 32 + sub * 4;
    const float4* __restrict__ urow1 = u_weight + (size_t)pu.y * 32 + sub * 4;
    const float4 t00 = urow0[0];
    const float4 t01 = urow0[1];
    const float4 t02 = urow0[2];
    const float4 t03 = urow0[3];
    const float4 t10 = urow1[0];
    const float4 t11 = urow1[1];
    const float4 t12 = urow1[2];
    const float4 t13 = urow1[3];

    // ---- PHASE 2: consume ----
    float uf0[16], uf1[16];
    uf0[0]  = t00.x; uf0[1]  = t00.y; uf0[2]  = t00.z; uf0[3]  = t00.w;
    uf0[4]  = t01.x; uf0[5]  = t01.y; uf0[6]  = t01.z; uf0[7]  = t01.w;
    uf0[8]  = t02.x; uf0[9]  = t02.y; uf0[10] = t02.z; uf0[11] = t02.w;
    uf0[12] = t03.x; uf0[13] = t03.y; uf0[14] = t03.z; uf0[15] = t03.w;
    uf1[0]  = t10.x; uf1[1]  = t10.y; uf1[2]  = t10.z; uf1[3]  = t10.w;
    uf1[4]  = t11.x; uf1[5]  = t11.y; uf1[6]  = t11.z; uf1[7]  = t11.w;
    uf1[8]  = t12.x; uf1[9]  = t12.y; uf1[10] = t12.z; uf1[11] = t12.w;
    uf1[12] = t13.x; uf1[13] = t13.y; uf1[14] = t13.z; uf1[15] = t13.w;

    float a0[N_NEG + 1], a1[N_NEG + 1];
    #pragma unroll
    for (int j = 0; j <= N_NEG; ++j) {
        a0[j] = dot16_fp8(w0[j], uf0);
        a1[j] = dot16_fp8(w1[j], uf1);
    }

    #pragma unroll
    for (int m = 1; m < 8; m <<= 1) {
        #pragma unroll
        for (int j = 0; j <= N_NEG; ++j) {
            a0[j] += __shfl_xor(a0[j], m, 64);
            a1[j] += __shfl_xor(a1[j], m, 64);
        }
    }

    float s0 = fminf(fmaxf(a0[0] * QINV, -10.0f), 10.0f);
    float s1 = fminf(fmaxf(a1[0] * QINV, -10.0f), 10.0f);
    float loss2 = softplus_log2(-s0) + softplus_log2(-s1);
    #pragma unroll
    for (int n = 0; n < N_NEG; ++n)
        loss2 -= softplus_log2(a0[n + 1] * QINV) + softplus_log2(a1[n + 1] * QINV);
    float loss = loss2 * 0.69314718f;   // loss(b0) + loss(b1), uniform in group

    // Butterfly over masks 8,16,32 sums the 8 distinct group values once each.
    #pragma unroll
    for (int m = 8; m < 64; m <<= 1) loss += __shfl_xor(loss, m, 64);

    __shared__ float smem[4];
    if (lane == 0) smem[wave] = loss;
    __syncthreads();
    if (tid == 0)
        atomicAdd(out, (smem[0] + smem[1] + smem[2] + smem[3]) * (1.0f / (float)BATCH));
}

// ---------- fp32 fallback if ws is too small ----------
__device__ __forceinline__ float dot4(float4 a, float4 b) {
    return a.x * b.x + a.y * b.y + a.z * b.z + a.w * b.w;
}

__global__ __launch_bounds__(256) void skipgram_loss_fp32_kernel(
    const int* __restrict__ pos_u,
    const int* __restrict__ pos_v,
    const int* __restrict__ neg_v,
    const float4* __restrict__ u_weight,
    const float4* __restrict__ v_weight,
    float* __restrict__ out)
{
    const int tid  = threadIdx.x;
    const int lane = tid & 63;
    const int wave = tid >> 6;
    const int sub  = lane & 7;
    const int grp  = lane >> 3;

    const int b = ((blockIdx.x * 4 + wave) * 8 + grp);

    const int iu = pos_u[b];
    const int iv = pos_v[b];

    const float4* __restrict__ urow = u_weight + iu * 32;
    float4 u0 = urow[0 * 8 + sub];
    float4 u1 = urow[1 * 8 + sub];
    float4 u2 = urow[2 * 8 + sub];
    float4 u3 = urow[3 * 8 + sub];

    const float4* __restrict__ vrow = v_weight + iv * 32;
    float p = dot4(u0, vrow[0 * 8 + sub]) + dot4(u1, vrow[1 * 8 + sub])
            + dot4(u2, vrow[2 * 8 + sub]) + dot4(u3, vrow[3 * 8 + sub]);

    float nd[N_NEG];
    #pragma unroll
    for (int n = 0; n < N_NEG; ++n) {
        const int idx = neg_v[b * N_NEG + n];
        const float4* __restrict__ wrow = v_weight + idx * 32;
        nd[n] = dot4(u0, wrow[0 * 8 + sub]) + dot4(u1, wrow[1 * 8 + sub])
              + dot4(u2, wrow[2 * 8 + sub]) + dot4(u3, wrow[3 * 8 + sub]);
    }

    #pragma unroll
    for (int m = 1; m < 8; m <<= 1) {
        p += __shfl_xor(p, m, 64);
        #pragma unroll
        for (int n = 0; n < N_NEG; ++n) nd[n] += __shfl_xor(nd[n], m, 64);
    }

    float s = fminf(fmaxf(p, -10.0f), 10.0f);
    float loss2 = softplus_log2(-s);
    #pragma unroll
    for (int n = 0; n < N_NEG; ++n) loss2 -= softplus_log2(nd[n]);
    float loss = loss2 * 0.69314718f;

    #pragma unroll
    for (int m = 8; m < 64; m <<= 1) loss += __shfl_xor(loss, m, 64);

    __shared__ float smem[4];
    if (lane == 0) smem[wave] = loss;
    __syncthreads();
    if (tid == 0)
        atomicAdd(out, (smem[0] + smem[1] + smem[2] + smem[3]) * (1.0f / (float)BATCH));
}

extern "C" void kernel_launch(void* const* d_in, const int* in_sizes, int n_in,
                              void* d_out, int out_size, void* d_ws, size_t ws_size,
                              hipStream_t stream) {
    const int*    pos_u    = (const int*)d_in[0];
    const int*    pos_v    = (const int*)d_in[1];
    const int*    neg_v    = (const int*)d_in[2];
    const float4* u_weight = (const float4*)d_in[3];
    const float4* v_weight = (const float4*)d_in[4];
    float* out = (float*)d_out;

    const size_t table_bytes = (size_t)VOCAB * DIM;        // 12.8 MB fp8
    if (ws_size >= table_bytes) {
        uint4* v8 = (uint4*)d_ws;
        const int qblocks = (VOCAB * DIM / 16) / 256;      // 3125
        quantize_v_kernel<<<qblocks, 256, 0, stream>>>(v_weight, v8, out);
        skipgram_loss_fp8_kernel<<<BLOCKS, 256, 0, stream>>>(
            pos_u, pos_v, neg_v, u_weight, v8, out);
    } else {
        zero_out_kernel<<<1, 1, 0, stream>>>(out);
        skipgram_loss_fp32_kernel<<<BATCH / 32, 256, 0, stream>>>(
            pos_u, pos_v, neg_v, u_weight, v_weight, out);
    }
}